// Round 5
// baseline (533.200 us; speedup 1.0000x reference)
//
#include <hip/hip_runtime.h>
#include <math.h>

typedef __attribute__((ext_vector_type(4))) float f32x4;
typedef __attribute__((ext_vector_type(2))) long lng2;

#define NCLS   50000
#define KSUB   3
#define DIM    512            // elements; fp8 row = 512 bytes
#define NROWSW (NCLS*KSUB)    // 150000
#define BQ     1024

#define SCALEF 30.0f
#define EPSC   1e-7f
#define COSM   0.8775825618903728f
#define SINM   0.4794255386042030f

#define BN     48             // weight rows per wave-tile (lcm(16,3))
#define TW     3              // 16-row MFMA tiles per wave-tile
#define COLS   256            // cols per block (E-LDS = 256*512 = 128 KB)
#define NJC    4              // col-chunks of 64
#define NTILES (NROWSW/BN)    // 3125
#define NRB    64             // row-block groups
#define GRID   (NRB*4)        // 256 blocks: rb = blk&63, colgroup = blk>>6
#define WSLOTS (NRB*8)        // 512 wave slots striding tiles

__device__ __forceinline__ float wave_sum(float v) {
#pragma unroll
  for (int m = 1; m < 64; m <<= 1) v += __shfl_xor(v, m, 64);
  return v;
}

__device__ __forceinline__ unsigned pack4_fp8(float a, float b, float c, float d) {
  int v = 0;
  v = __builtin_amdgcn_cvt_pk_fp8_f32(a, b, v, false);
  v = __builtin_amdgcn_cvt_pk_fp8_f32(c, d, v, true);
  return (unsigned)v;
}

__device__ __forceinline__ float eterm(float v) {
  v = fminf(fmaxf(v, -1.f + EPSC), 1.f - EPSC);
  return __expf(SCALEF * v);
}

// K0: normalize embeddings, store fp8 e4m3 [1024][512]
__global__ __launch_bounds__(64) void k_norm_e(const float* __restrict__ E,
                                               unsigned char* __restrict__ En8) {
  const int b = blockIdx.x, l = threadIdx.x;
  const float4* p = reinterpret_cast<const float4*>(E + (size_t)b * DIM + l * 8);
  float4 a = p[0], c = p[1];
  float ss = a.x*a.x + a.y*a.y + a.z*a.z + a.w*a.w
           + c.x*c.x + c.y*c.y + c.z*c.z + c.w*c.w;
  ss = wave_sum(ss);
  float inv = rsqrtf(ss);
  uint2 o;
  o.x = pack4_fp8(a.x*inv, a.y*inv, a.z*inv, a.w*inv);
  o.y = pack4_fp8(c.x*inv, c.y*inv, c.z*inv, c.w*inv);
  *reinterpret_cast<uint2*>(En8 + (size_t)b * DIM + l * 8) = o;
}

// K-pre: normalize weight rows, store fp8 e4m3 [150000][512]
__global__ __launch_bounds__(256) void k_prenorm(const float* __restrict__ W,
                                                 unsigned char* __restrict__ Wn8) {
  const int row = blockIdx.x * 4 + (threadIdx.x >> 6);
  const int l = threadIdx.x & 63;
  const float4* p = reinterpret_cast<const float4*>(W + (size_t)row * DIM + l * 8);
  float4 a = p[0], d = p[1];
  float ss = a.x*a.x + a.y*a.y + a.z*a.z + a.w*a.w
           + d.x*d.x + d.y*d.y + d.z*d.z + d.w*d.w;
  ss = wave_sum(ss);
  float inv = rsqrtf(ss);
  uint2 o;
  o.x = pack4_fp8(a.x*inv, a.y*inv, a.z*inv, a.w*inv);
  o.y = pack4_fp8(d.x*inv, d.y*inv, d.z*inv, d.w*inv);
  *reinterpret_cast<uint2*>(Wn8 + (size_t)row * DIM + l * 8) = o;
}

// K2: exact f32 target-class cosine + margin terms (verified)
__global__ __launch_bounds__(64) void k_target(const float* __restrict__ E,
                                               const int* __restrict__ lab,
                                               const float* __restrict__ W,
                                               float* __restrict__ delta,
                                               float* __restrict__ tl) {
  const int b = blockIdx.x, l = threadIdx.x;
  const float4* pe = reinterpret_cast<const float4*>(E + (size_t)b * DIM + l * 8);
  float4 e0 = pe[0], e1 = pe[1];
  float es = e0.x*e0.x + e0.y*e0.y + e0.z*e0.z + e0.w*e0.w
           + e1.x*e1.x + e1.y*e1.y + e1.z*e1.z + e1.w*e1.w;
  es = wave_sum(es);
  const int L = lab[b];
  float mx = -2.f;
#pragma unroll
  for (int k = 0; k < KSUB; ++k) {
    const float4* pw = reinterpret_cast<const float4*>(W + (size_t)(L * KSUB + k) * DIM + l * 8);
    float4 w0 = pw[0], w1 = pw[1];
    float ds = e0.x*w0.x + e0.y*w0.y + e0.z*w0.z + e0.w*w0.w
             + e1.x*w1.x + e1.y*w1.y + e1.z*w1.z + e1.w*w1.w;
    float ws = w0.x*w0.x + w0.y*w0.y + w0.z*w0.z + w0.w*w0.w
             + w1.x*w1.x + w1.y*w1.y + w1.z*w1.z + w1.w*w1.w;
    ds = wave_sum(ds);
    ws = wave_sum(ws);
    float ck = ds * rsqrtf(es * ws);
    mx = fmaxf(mx, ck);
  }
  if (l == 0) {
    float cc = fminf(fmaxf(mx, -1.f + EPSC), 1.f - EPSC);
    float sn = sqrtf(fmaxf(1.f - cc * cc, 0.f));
    float mg = cc * COSM - sn * SINM;           // cos(arccos(cc)+m)
    delta[b] = __expf(SCALEF * mg) - __expf(SCALEF * cc);
    tl[b]    = SCALEF * mg;
  }
}

// K1: E resident in LDS (256 cols, swizzled for conflict-free ds_read_b128);
// W streamed into registers (48 rows/wave); no barrier in main loop.
// Each wave owns tile-slots wslot, wslot+512, ...; per-wave partials go to
// Zp[wslot] (FIX vs R4: wv is in the index — 8 waves no longer race).
__global__ __launch_bounds__(512, 2) void k_main(const unsigned char* __restrict__ Wn8,
                                                 const unsigned char* __restrict__ En8,
                                                 float* __restrict__ Zp) {
  extern __shared__ __align__(16) unsigned char elds[];   // COLS*512 = 128 KB
  const int tid  = threadIdx.x;
  const int lane = tid & 63;
  const int wv   = tid >> 6;
  const int g    = lane >> 4;
  const int c    = lane & 15;
  const int rb       = blockIdx.x & (NRB - 1);
  const int colgroup = blockIdx.x >> 6;

  // ---- one-time E-LDS fill. LDS slot s of col holds (ks2,g') = decode(s ^ (col&7)),
  // 16B = [bytes ks2*64+g'*8 .. +8) | [ks2*64+32+g'*8 .. +8) ----
  const unsigned char* Eg = En8 + (size_t)colgroup * COLS * DIM;
#pragma unroll
  for (int i = 0; i < 16; ++i) {
    const int idx  = i * 512 + tid;        // 0..8191
    const int col  = idx >> 5;
    const int slot = idx & 31;
    const int s    = slot ^ (col & 7);
    const int ks2  = s >> 2;
    const int gg   = s & 3;
    const unsigned char* src = Eg + (size_t)col * DIM + ks2 * 64 + gg * 8;
    lng2 v;
    v[0] = *reinterpret_cast<const long*>(src);
    v[1] = *reinterpret_cast<const long*>(src + 32);
    *reinterpret_cast<lng2*>(elds + col * DIM + slot * 16) = v;
  }
  __syncthreads();

  float zreg[NJC][4];
#pragma unroll
  for (int jc = 0; jc < NJC; ++jc)
#pragma unroll
    for (int j = 0; j < 4; ++j) zreg[jc][j] = 0.f;

  const int wslot = rb * 8 + wv;           // 0..511

  for (int tile = wslot; tile < NTILES; tile += WSLOTS) {
    // ---- stream this wave's 48-row W tile into registers ----
    long wfr[TW][8][2];
#pragma unroll
    for (int t = 0; t < TW; ++t)
#pragma unroll
      for (int ks2 = 0; ks2 < 8; ++ks2) {
        const unsigned char* rp =
            Wn8 + ((size_t)tile * BN + t * 16 + c) * DIM + ks2 * 64 + g * 8;
        wfr[t][ks2][0] = *reinterpret_cast<const long*>(rp);
        wfr[t][ks2][1] = *reinterpret_cast<const long*>(rp + 32);
      }

#pragma unroll
    for (int jc = 0; jc < NJC; ++jc) {
      f32x4 acc[TW][4];
#pragma unroll
      for (int t = 0; t < TW; ++t)
#pragma unroll
        for (int j = 0; j < 4; ++j) acc[t][j] = (f32x4){0.f, 0.f, 0.f, 0.f};

#pragma unroll
      for (int ks2 = 0; ks2 < 8; ++ks2) {
        lng2 bfr[4];
#pragma unroll
        for (int j = 0; j < 4; ++j) {
          const int col = jc * 64 + j * 16 + c;
          const int slot = (ks2 * 4 + g) ^ (c & 7);
          bfr[j] = *reinterpret_cast<const lng2*>(elds + col * DIM + slot * 16);
        }
#pragma unroll
        for (int t = 0; t < TW; ++t)
#pragma unroll
          for (int j = 0; j < 4; ++j) {
            acc[t][j] = __builtin_amdgcn_mfma_f32_16x16x32_fp8_fp8(
                wfr[t][ks2][0], bfr[j][0], acc[t][j], 0, 0, 0);
            acc[t][j] = __builtin_amdgcn_mfma_f32_16x16x32_fp8_fp8(
                wfr[t][ks2][1], bfr[j][1], acc[t][j], 0, 0, 0);
          }
      }

      // ---- epilogue: max over sub-center triples (verified), exp, per-col sums ----
#pragma unroll
      for (int j = 0; j < 4; ++j) {
        float zc = 0.f;
#pragma unroll
        for (int t = 0; t < TW; ++t) {
          float s0, s1;
          if (t + 1 < TW) {
            s0 = (g == 0) ? acc[t + 1][j][0] : acc[t][j][0];
            s1 = (g == 0) ? acc[t + 1][j][1] : acc[t][j][1];
          } else {
            s0 = (g == 0) ? -2.f : acc[t][j][0];
            s1 = (g == 0) ? -2.f : acc[t][j][1];
          }
          float e0 = __shfl(s0, (lane + 16) & 63, 64);
          float e1 = __shfl(s1, (lane + 16) & 63, 64);
          const int m = (4 * t + g) % 3;
          float a0 = acc[t][j][0], a1 = acc[t][j][1], a2 = acc[t][j][2], a3 = acc[t][j][3];
          if (m == 0)      zc += eterm(fmaxf(fmaxf(a0, a1), a2)) + eterm(fmaxf(fmaxf(a3, e0), e1));
          else if (m == 1) zc += eterm(fmaxf(fmaxf(a2, a3), e0));
          else             zc += eterm(fmaxf(fmaxf(a1, a2), a3));
        }
        zc += __shfl_xor(zc, 16, 64);
        zc += __shfl_xor(zc, 32, 64);
        zreg[jc][j] += zc;
      }
    }
  }

  if (g == 0) {
#pragma unroll
    for (int jc = 0; jc < NJC; ++jc)
#pragma unroll
      for (int j = 0; j < 4; ++j)
        Zp[(size_t)wslot * BQ + colgroup * COLS + jc * 64 + j * 16 + c] = zreg[jc][j];
  }
}

// K3: Z[b] = sum over 512 wave-slot partials; per-row loss; block partial sums
__global__ __launch_bounds__(256) void k_reduce(const float* __restrict__ Zp,
                                                const float* __restrict__ delta,
                                                const float* __restrict__ tl,
                                                float* __restrict__ part) {
  const int b = blockIdx.x * 256 + threadIdx.x;
  float z = 0.f;
#pragma unroll 8
  for (int nb = 0; nb < WSLOTS; ++nb) z += Zp[(size_t)nb * BQ + b];
  float lossb = logf(z + delta[b]) - tl[b];
  __shared__ float sm[256];
  sm[threadIdx.x] = lossb;
  __syncthreads();
#pragma unroll
  for (int s = 128; s > 0; s >>= 1) {
    if (threadIdx.x < s) sm[threadIdx.x] += sm[threadIdx.x + s];
    __syncthreads();
  }
  if (threadIdx.x == 0) part[blockIdx.x] = sm[0];
}

__global__ void k_final(const float* __restrict__ part, float* __restrict__ out) {
  out[0] = (part[0] + part[1] + part[2] + part[3]) * (1.0f / BQ);
}

extern "C" void kernel_launch(void* const* d_in, const int* in_sizes, int n_in,
                              void* d_out, int out_size, void* d_ws, size_t ws_size,
                              hipStream_t stream) {
  const float* E  = (const float*)d_in[0];
  const int* lab  = (const int*)d_in[1];
  const float* W  = (const float*)d_in[2];

  char* ws = (char*)d_ws;
  unsigned char* En8 = (unsigned char*)ws;                          // 512 KB
  unsigned char* Wn8 = (unsigned char*)(ws + (size_t)BQ * DIM);     // 76.8 MB
  char* after = ws + (size_t)BQ * DIM + (size_t)NROWSW * DIM;
  float* Zp    = (float*)after;                                     // 512*1024*4 = 2 MB
  float* delta = Zp + (size_t)WSLOTS * BQ;
  float* tl    = delta + BQ;
  float* part  = tl + BQ;

  hipFuncSetAttribute(reinterpret_cast<const void*>(&k_main),
                      hipFuncAttributeMaxDynamicSharedMemorySize, COLS * DIM);

  hipLaunchKernelGGL(k_prenorm, dim3(NROWSW / 4), dim3(256), 0, stream, W, Wn8);
  hipLaunchKernelGGL(k_norm_e,  dim3(BQ),         dim3(64),  0, stream, E, En8);
  hipLaunchKernelGGL(k_target,  dim3(BQ),         dim3(64),  0, stream, E, lab, W, delta, tl);
  hipLaunchKernelGGL(k_main,    dim3(GRID),       dim3(512), COLS * DIM, stream, Wn8, En8, Zp);
  hipLaunchKernelGGL(k_reduce,  dim3(4),          dim3(256), 0, stream, Zp, delta, tl, part);
  hipLaunchKernelGGL(k_final,   dim3(1),          dim3(1),   0, stream, part, (float*)d_out);
}

// Round 6
// 224.207 us; speedup vs baseline: 2.3782x; 2.3782x over previous
//
#include <hip/hip_runtime.h>
#include <math.h>

typedef __attribute__((ext_vector_type(4))) float f32x4;

#define NCLS   50000
#define KSUB   3
#define DIM    512            // elements; fp8 row = 512 bytes
#define NROWSW (NCLS*KSUB)    // 150000
#define BQ     1024

#define SCALEF 30.0f
#define EPSC   1e-7f
#define COSM   0.8775825618903728f
#define SINM   0.4794255386042030f

#define BN     48             // weight rows per tile (lcm(16,3))
#define TW     3              // 16-row MFMA tiles
#define NJ     2              // 16-col B subtiles per wave (32 cols/wave, 256/block)
#define NTILES (NROWSW/BN)    // 3125
#define NRG    64             // row groups (blocks splitting the tile range)
#define NCG    4              // col groups of 256
#define TILEB  (BN*DIM)       // 24576 B per LDS buffer

__device__ __forceinline__ float wave_sum(float v) {
#pragma unroll
  for (int m = 1; m < 64; m <<= 1) v += __shfl_xor(v, m, 64);
  return v;
}

__device__ __forceinline__ unsigned pack4_fp8(float a, float b, float c, float d) {
  int v = 0;
  v = __builtin_amdgcn_cvt_pk_fp8_f32(a, b, v, false);
  v = __builtin_amdgcn_cvt_pk_fp8_f32(c, d, v, true);
  return (unsigned)v;
}

__device__ __forceinline__ float eterm(float v) {
  v = fminf(fmaxf(v, -1.f + EPSC), 1.f - EPSC);
  return __expf(SCALEF * v);
}

// K0: normalize embeddings, store fp8 e4m3 [1024][512]
__global__ __launch_bounds__(64) void k_norm_e(const float* __restrict__ E,
                                               unsigned char* __restrict__ En8) {
  const int b = blockIdx.x, l = threadIdx.x;
  const float4* p = reinterpret_cast<const float4*>(E + (size_t)b * DIM + l * 8);
  float4 a = p[0], c = p[1];
  float ss = a.x*a.x + a.y*a.y + a.z*a.z + a.w*a.w
           + c.x*c.x + c.y*c.y + c.z*c.z + c.w*c.w;
  ss = wave_sum(ss);
  float inv = rsqrtf(ss);
  uint2 o;
  o.x = pack4_fp8(a.x*inv, a.y*inv, a.z*inv, a.w*inv);
  o.y = pack4_fp8(c.x*inv, c.y*inv, c.z*inv, c.w*inv);
  *reinterpret_cast<uint2*>(En8 + (size_t)b * DIM + l * 8) = o;
}

// K-pre: normalize weight rows, store fp8 e4m3 [150000][512]
__global__ __launch_bounds__(256) void k_prenorm(const float* __restrict__ W,
                                                 unsigned char* __restrict__ Wn8) {
  const int row = blockIdx.x * 4 + (threadIdx.x >> 6);
  const int l = threadIdx.x & 63;
  const float4* p = reinterpret_cast<const float4*>(W + (size_t)row * DIM + l * 8);
  float4 a = p[0], d = p[1];
  float ss = a.x*a.x + a.y*a.y + a.z*a.z + a.w*a.w
           + d.x*d.x + d.y*d.y + d.z*d.z + d.w*d.w;
  ss = wave_sum(ss);
  float inv = rsqrtf(ss);
  uint2 o;
  o.x = pack4_fp8(a.x*inv, a.y*inv, a.z*inv, a.w*inv);
  o.y = pack4_fp8(d.x*inv, d.y*inv, d.z*inv, d.w*inv);
  *reinterpret_cast<uint2*>(Wn8 + (size_t)row * DIM + l * 8) = o;
}

// K2: exact f32 target-class cosine + margin terms (verified)
__global__ __launch_bounds__(64) void k_target(const float* __restrict__ E,
                                               const int* __restrict__ lab,
                                               const float* __restrict__ W,
                                               float* __restrict__ delta,
                                               float* __restrict__ tl) {
  const int b = blockIdx.x, l = threadIdx.x;
  const float4* pe = reinterpret_cast<const float4*>(E + (size_t)b * DIM + l * 8);
  float4 e0 = pe[0], e1 = pe[1];
  float es = e0.x*e0.x + e0.y*e0.y + e0.z*e0.z + e0.w*e0.w
           + e1.x*e1.x + e1.y*e1.y + e1.z*e1.z + e1.w*e1.w;
  es = wave_sum(es);
  const int L = lab[b];
  float mx = -2.f;
#pragma unroll
  for (int k = 0; k < KSUB; ++k) {
    const float4* pw = reinterpret_cast<const float4*>(W + (size_t)(L * KSUB + k) * DIM + l * 8);
    float4 w0 = pw[0], w1 = pw[1];
    float ds = e0.x*w0.x + e0.y*w0.y + e0.z*w0.z + e0.w*w0.w
             + e1.x*w1.x + e1.y*w1.y + e1.z*w1.z + e1.w*w1.w;
    float ws = w0.x*w0.x + w0.y*w0.y + w0.z*w0.z + w0.w*w0.w
             + w1.x*w1.x + w1.y*w1.y + w1.z*w1.z + w1.w*w1.w;
    ds = wave_sum(ds);
    ws = wave_sum(ws);
    float ck = ds * rsqrtf(es * ws);
    mx = fmaxf(mx, ck);
  }
  if (l == 0) {
    float cc = fminf(fmaxf(mx, -1.f + EPSC), 1.f - EPSC);
    float sn = sqrtf(fmaxf(1.f - cc * cc, 0.f));
    float mg = cc * COSM - sn * SINM;           // cos(arccos(cc)+m)
    delta[b] = __expf(SCALEF * mg) - __expf(SCALEF * cc);
    tl[b]    = SCALEF * mg;
  }
}

// stage one 48-row W tile (24 KB) into LDS via global_load_lds.
// 16B chunk m of row r in LDS holds global chunk m ^ (r&7) (read-side swizzle).
// 3 issues/thread; each issue: wave covers 2 rows, fully coalesced (permuted within row).
__device__ __forceinline__ void stage_tile(const unsigned char* __restrict__ Wt,
                                           unsigned char* lbuf, int wv, int lane) {
#pragma unroll
  for (int i = 0; i < 3; ++i) {
    const int r = i * 16 + wv * 2 + (lane >> 5);
    const int m = (lane & 31) ^ (r & 7);
    const unsigned char* src = Wt + (size_t)r * DIM + m * 16;
    __builtin_amdgcn_global_load_lds(
        (const __attribute__((address_space(1))) unsigned int*)src,
        (__attribute__((address_space(3))) unsigned int*)(lbuf + (i * 16 + wv * 2) * DIM),
        16, 0, 0);
  }
}

// K1: E-fragments in REGISTERS (32 cols x K=512 per wave = 64 VGPRs, loaded once);
// W tiles in dbuf LDS (2x24 KB) via global_load_lds; 2-phase schedule.
// Block (rg, cg): tiles rg, rg+64, ...; cols cg*256 .. +256.
__global__ __launch_bounds__(512, 1) void k_main(const unsigned char* __restrict__ Wn8,
                                                 const unsigned char* __restrict__ En8,
                                                 float* __restrict__ Zp) {
  __shared__ __align__(16) unsigned char wlds[2 * TILEB];   // 48 KB
  const int tid  = threadIdx.x;
  const int lane = tid & 63;
  const int wv   = tid >> 6;
  const int g    = lane >> 4;
  const int c    = lane & 15;
  const int rg   = blockIdx.x & (NRG - 1);   // partners (same rg) share XCD: blk%8 = rg%8
  const int cg   = blockIdx.x >> 6;

  // ---- load this wave's E fragments once: 2 x 16 longs = 64 VGPRs ----
  long bfr[NJ][16];
#pragma unroll
  for (int j = 0; j < NJ; ++j) {
    const int col = cg * 256 + wv * 32 + j * 16 + c;
#pragma unroll
    for (int ks = 0; ks < 16; ++ks)
      bfr[j][ks] = *reinterpret_cast<const long*>(
          En8 + (size_t)col * DIM + ks * 32 + g * 8);
  }

  float zreg[NJ];
#pragma unroll
  for (int j = 0; j < NJ; ++j) zreg[j] = 0.f;

  int tile = rg;
  stage_tile(Wn8 + (size_t)tile * TILEB, wlds, wv, lane);
  __syncthreads();
  int cur = 0;

  for (; tile < NTILES; tile += NRG) {
    const int nxt = tile + NRG;
    if (nxt < NTILES)
      stage_tile(Wn8 + (size_t)nxt * TILEB, wlds + (cur ^ 1) * TILEB, wv, lane);

    const unsigned char* lbuf = wlds + cur * TILEB;

    f32x4 acc[TW][NJ];
#pragma unroll
    for (int t = 0; t < TW; ++t)
#pragma unroll
      for (int j = 0; j < NJ; ++j) acc[t][j] = (f32x4){0.f, 0.f, 0.f, 0.f};

#pragma unroll
    for (int ks2 = 0; ks2 < 8; ++ks2) {
#pragma unroll
      for (int t = 0; t < TW; ++t) {
        const int r = t * 16 + c;
        const long* lrow = reinterpret_cast<const long*>(lbuf + r * DIM);
        const int sw = (r & 7) << 1;
        long a0 = lrow[(ks2 * 8 + g) ^ sw];
        long a1 = lrow[(ks2 * 8 + 4 + g) ^ sw];
#pragma unroll
        for (int j = 0; j < NJ; ++j) {
          acc[t][j] = __builtin_amdgcn_mfma_f32_16x16x32_fp8_fp8(
              a0, bfr[j][2 * ks2], acc[t][j], 0, 0, 0);
          acc[t][j] = __builtin_amdgcn_mfma_f32_16x16x32_fp8_fp8(
              a1, bfr[j][2 * ks2 + 1], acc[t][j], 0, 0, 0);
        }
      }
    }

    // ---- epilogue: max over sub-center triples (verified), exp, per-col sums ----
#pragma unroll
    for (int j = 0; j < NJ; ++j) {
      float zc = 0.f;
#pragma unroll
      for (int t = 0; t < TW; ++t) {
        float s0, s1;
        if (t + 1 < TW) {
          s0 = (g == 0) ? acc[t + 1][j][0] : acc[t][j][0];
          s1 = (g == 0) ? acc[t + 1][j][1] : acc[t][j][1];
        } else {
          s0 = (g == 0) ? -2.f : acc[t][j][0];
          s1 = (g == 0) ? -2.f : acc[t][j][1];
        }
        float e0 = __shfl(s0, (lane + 16) & 63, 64);
        float e1 = __shfl(s1, (lane + 16) & 63, 64);
        const int m = (4 * t + g) % 3;
        float a0 = acc[t][j][0], a1 = acc[t][j][1], a2 = acc[t][j][2], a3 = acc[t][j][3];
        if (m == 0)      zc += eterm(fmaxf(fmaxf(a0, a1), a2)) + eterm(fmaxf(fmaxf(a3, e0), e1));
        else if (m == 1) zc += eterm(fmaxf(fmaxf(a2, a3), e0));
        else             zc += eterm(fmaxf(fmaxf(a1, a2), a3));
      }
      zc += __shfl_xor(zc, 16, 64);
      zc += __shfl_xor(zc, 32, 64);
      zreg[j] += zc;
    }

    __syncthreads();   // next-tile staging drained + all waves done with cur
    cur ^= 1;
  }

  if (g == 0) {
#pragma unroll
    for (int j = 0; j < NJ; ++j)
      Zp[(size_t)rg * BQ + cg * 256 + wv * 32 + j * 16 + c] = zreg[j];
  }
}

// K3: Z[b] = sum over 64 row-group partials; per-row loss; block partial sums
__global__ __launch_bounds__(256) void k_reduce(const float* __restrict__ Zp,
                                                const float* __restrict__ delta,
                                                const float* __restrict__ tl,
                                                float* __restrict__ part) {
  const int b = blockIdx.x * 256 + threadIdx.x;
  float z = 0.f;
#pragma unroll 8
  for (int nb = 0; nb < NRG; ++nb) z += Zp[(size_t)nb * BQ + b];
  float lossb = logf(z + delta[b]) - tl[b];
  __shared__ float sm[256];
  sm[threadIdx.x] = lossb;
  __syncthreads();
#pragma unroll
  for (int s = 128; s > 0; s >>= 1) {
    if (threadIdx.x < s) sm[threadIdx.x] += sm[threadIdx.x + s];
    __syncthreads();
  }
  if (threadIdx.x == 0) part[blockIdx.x] = sm[0];
}

__global__ void k_final(const float* __restrict__ part, float* __restrict__ out) {
  out[0] = (part[0] + part[1] + part[2] + part[3]) * (1.0f / BQ);
}

extern "C" void kernel_launch(void* const* d_in, const int* in_sizes, int n_in,
                              void* d_out, int out_size, void* d_ws, size_t ws_size,
                              hipStream_t stream) {
  const float* E  = (const float*)d_in[0];
  const int* lab  = (const int*)d_in[1];
  const float* W  = (const float*)d_in[2];

  char* ws = (char*)d_ws;
  unsigned char* En8 = (unsigned char*)ws;                          // 512 KB
  unsigned char* Wn8 = (unsigned char*)(ws + (size_t)BQ * DIM);     // 76.8 MB
  char* after = ws + (size_t)BQ * DIM + (size_t)NROWSW * DIM;
  float* Zp    = (float*)after;                                     // 64*1024*4 = 256 KB
  float* delta = Zp + (size_t)NRG * BQ;
  float* tl    = delta + BQ;
  float* part  = tl + BQ;

  hipLaunchKernelGGL(k_prenorm, dim3(NROWSW / 4), dim3(256), 0, stream, W, Wn8);
  hipLaunchKernelGGL(k_norm_e,  dim3(BQ),         dim3(64),  0, stream, E, En8);
  hipLaunchKernelGGL(k_target,  dim3(BQ),         dim3(64),  0, stream, E, lab, W, delta, tl);
  hipLaunchKernelGGL(k_main,    dim3(NRG * NCG),  dim3(512), 0, stream, Wn8, En8, Zp);
  hipLaunchKernelGGL(k_reduce,  dim3(4),          dim3(256), 0, stream, Zp, delta, tl, part);
  hipLaunchKernelGGL(k_final,   dim3(1),          dim3(1),   0, stream, part, (float*)d_out);
}